// Round 1
// baseline (4343.378 us; speedup 1.0000x reference)
//
#include <hip/hip_runtime.h>
#include <hip/hip_bf16.h>

#define N_NODES 100000
#define N_EDGES 1600000
#define HID 128
#define N_GRAPHS 512

// ---------------- degree / normalization ----------------

__global__ void k_deg_init(int* degi, int n) {
    int i = blockIdx.x * 256 + threadIdx.x;
    if (i < n) degi[i] = 1;  // self-loop
}

__global__ void k_deg_count(const int* __restrict__ dst, int e, int* __restrict__ degi) {
    int i = blockIdx.x * 256 + threadIdx.x;
    if (i < e) atomicAdd(&degi[dst[i]], 1);
}

__global__ void k_deg_fin(const int* __restrict__ degi, float* __restrict__ dis,
                          float* __restrict__ dinv, int n) {
    int i = blockIdx.x * 256 + threadIdx.x;
    if (i < n) {
        float d = (float)degi[i];
        dis[i] = rsqrtf(d);
        dinv[i] = 1.0f / d;
    }
}

// ---------------- layer 1: x (N x 7) @ W1 (7 x 128) ----------------

__global__ void k_linear1(const float* __restrict__ x, const float* __restrict__ W1,
                          float* __restrict__ hw, int n) {
    __shared__ float W1s[7 * 128];
    int tid = threadIdx.x;
    for (int i = tid; i < 7 * 128; i += 256) W1s[i] = W1[i];
    __syncthreads();
    int node = blockIdx.x * 2 + (tid >> 7);
    if (node >= n) return;
    int c = tid & 127;
    const float* xr = x + (size_t)node * 7;
    float acc = 0.f;
#pragma unroll
    for (int k = 0; k < 7; ++k) acc += xr[k] * W1s[k * 128 + c];
    hw[(size_t)node * 128 + c] = acc;
}

// ---------------- self-loop init: agg = hw * (1/deg) ----------------

__global__ void k_selfloop(const float4* __restrict__ hw4, const float* __restrict__ dinv,
                           float4* __restrict__ agg4, int n4) {
    int i = blockIdx.x * 256 + threadIdx.x;
    if (i >= n4) return;
    float s = dinv[i >> 5];  // 32 float4 per node row
    float4 v = hw4[i];
    float4 o;
    o.x = v.x * s; o.y = v.y * s; o.z = v.z * s; o.w = v.w * s;
    agg4[i] = o;
}

// ---------------- edge scatter-add: agg[dst] += hw[src] * dis[s]*dis[d] ----------------

__global__ void k_edge_agg(const int* __restrict__ ei, const float* __restrict__ dis,
                           const float* __restrict__ hw, float* __restrict__ agg, int e) {
    int idx = blockIdx.x * 256 + threadIdx.x;
    int eid = idx >> 6;       // 64 lanes per edge
    if (eid >= e) return;
    int lane = idx & 63;
    int s = ei[eid];
    int d = ei[N_EDGES + eid];
    float w = dis[s] * dis[d];
    float2 v = ((const float2*)hw)[(size_t)s * 64 + lane];
    float* ap = agg + (size_t)d * 128 + lane * 2;
    atomicAdd(ap, v.x * w);
    atomicAdd(ap + 1, v.y * w);
}

// ---------------- fused relu(agg+b) @ W (128x128) ----------------
// Stages full W in LDS once per block; grid-stride over node chunks of 8.

#define GN 8
__launch_bounds__(256) __global__
void k_gemm128_fused(const float* __restrict__ aggin, const float* __restrict__ b,
                     const float* __restrict__ W, float* __restrict__ hwout, int n) {
    __shared__ float Ws[128 * 128];
    __shared__ float hs[GN * 128];
    int tid = threadIdx.x;
    const float4* W4 = (const float4*)W;
    float4* Ws4 = (float4*)Ws;
    for (int i = tid; i < 128 * 32; i += 256) Ws4[i] = W4[i];
    float4 bb = ((const float4*)b)[tid & 31];
    __syncthreads();

    int nsub = tid >> 5;   // 0..7 node slot
    int cg = tid & 31;     // float4 channel group
    for (int base = blockIdx.x * GN; base < n; base += gridDim.x * GN) {
        int nload = base + nsub;
        float4 v = make_float4(0.f, 0.f, 0.f, 0.f);
        if (nload < n) {
            v = ((const float4*)aggin)[(size_t)nload * 32 + cg];
            v.x = fmaxf(v.x + bb.x, 0.f);
            v.y = fmaxf(v.y + bb.y, 0.f);
            v.z = fmaxf(v.z + bb.z, 0.f);
            v.w = fmaxf(v.w + bb.w, 0.f);
        }
        __syncthreads();   // previous iteration's reads done
        ((float4*)hs)[tid] = v;
        __syncthreads();
        int node = base + nsub;
        if (node < n) {
            float4 acc = make_float4(0.f, 0.f, 0.f, 0.f);
            const float* hrow = &hs[nsub * 128];
#pragma unroll 8
            for (int k = 0; k < 128; ++k) {
                float hv = hrow[k];
                float4 wv = Ws4[k * 32 + cg];
                acc.x += hv * wv.x; acc.y += hv * wv.y;
                acc.z += hv * wv.z; acc.w += hv * wv.w;
            }
            ((float4*)hwout)[(size_t)node * 32 + cg] = acc;
        }
    }
}

// ---------------- pooling: segment_max(relu(agg+b)) via atomicMax on float bits ----------------

__global__ void k_pool_max(const float* __restrict__ agg, const float* __restrict__ b,
                           const int* __restrict__ batch, unsigned* __restrict__ pooled, int n) {
    int idx = blockIdx.x * 256 + threadIdx.x;
    int node = idx >> 7;
    if (node >= n) return;
    int c = idx & 127;
    int g = batch[node];
    float v = agg[(size_t)node * 128 + c] + b[c];
    v = fmaxf(v, 0.f);
    atomicMax(&pooled[(size_t)g * 128 + c], __float_as_uint(v));
}

// ---------------- head: out[g] = pooled[g] @ Wl + bl ----------------

__global__ void k_final(const float* __restrict__ pooled, const float* __restrict__ Wl,
                        const float* __restrict__ bl, float* __restrict__ out) {
    int g = blockIdx.x;
    int t = threadIdx.x;  // 64 threads
    float p0 = pooled[(size_t)g * 128 + t];
    float p1 = pooled[(size_t)g * 128 + t + 64];
    float a0 = p0 * Wl[t * 2 + 0] + p1 * Wl[(t + 64) * 2 + 0];
    float a1 = p0 * Wl[t * 2 + 1] + p1 * Wl[(t + 64) * 2 + 1];
#pragma unroll
    for (int off = 32; off > 0; off >>= 1) {
        a0 += __shfl_down(a0, off);
        a1 += __shfl_down(a1, off);
    }
    if (t == 0) {
        out[g * 2 + 0] = a0 + bl[0];
        out[g * 2 + 1] = a1 + bl[1];
    }
}

// ---------------- launch ----------------

extern "C" void kernel_launch(void* const* d_in, const int* in_sizes, int n_in,
                              void* d_out, int out_size, void* d_ws, size_t ws_size,
                              hipStream_t stream) {
    const float* x  = (const float*)d_in[0];
    const int*   ei = (const int*)d_in[1];
    const int*   batch = (const int*)d_in[2];
    const float* W1 = (const float*)d_in[3];
    const float* b1 = (const float*)d_in[4];
    const float* W2 = (const float*)d_in[5];
    const float* b2 = (const float*)d_in[6];
    const float* W3 = (const float*)d_in[7];
    const float* b3 = (const float*)d_in[8];
    const float* Wl = (const float*)d_in[9];
    const float* bl = (const float*)d_in[10];
    float* out = (float*)d_out;

    const int N = N_NODES, E = N_EDGES;

    // workspace layout (floats)
    char* ws = (char*)d_ws;
    float* bufA = (float*)ws;                               // N*128 (hw)
    float* bufB = bufA + (size_t)N * 128;                   // N*128 (agg)
    unsigned* pooled = (unsigned*)(bufB + (size_t)N * 128); // G*128
    float* dis  = (float*)(pooled + (size_t)N_GRAPHS * 128);
    float* dinv = dis + N;
    int*   degi = (int*)(dinv + N);

    int nb256 = (N + 255) / 256;
    int eb256 = (E + 255) / 256;

    // degrees + norms
    k_deg_init<<<nb256, 256, 0, stream>>>(degi, N);
    k_deg_count<<<eb256, 256, 0, stream>>>(ei + E, E, degi);  // dst row
    k_deg_fin<<<nb256, 256, 0, stream>>>(degi, dis, dinv, N);

    int n4 = N * 32;                     // float4 count of an N x 128 buffer
    int sb = (n4 + 255) / 256;           // 12500
    int egrid = (E * 64 + 255) / 256;    // 400000
    int gemm_grid = 512;                 // 2 blocks/CU (LDS-limited)

    // layer 1
    k_linear1<<<(N + 1) / 2, 256, 0, stream>>>(x, W1, bufA, N);
    k_selfloop<<<sb, 256, 0, stream>>>((const float4*)bufA, dinv, (float4*)bufB, n4);
    k_edge_agg<<<egrid, 256, 0, stream>>>(ei, dis, bufA, bufB, E);

    // layer 2 (relu(agg1+b1) @ W2)
    k_gemm128_fused<<<gemm_grid, 256, 0, stream>>>(bufB, b1, W2, bufA, N);
    k_selfloop<<<sb, 256, 0, stream>>>((const float4*)bufA, dinv, (float4*)bufB, n4);
    k_edge_agg<<<egrid, 256, 0, stream>>>(ei, dis, bufA, bufB, E);

    // layer 3 (relu(agg2+b2) @ W3)
    k_gemm128_fused<<<gemm_grid, 256, 0, stream>>>(bufB, b2, W3, bufA, N);
    k_selfloop<<<sb, 256, 0, stream>>>((const float4*)bufA, dinv, (float4*)bufB, n4);
    k_edge_agg<<<egrid, 256, 0, stream>>>(ei, dis, bufA, bufB, E);

    // pooling: relu(agg3+b3) -> segment max
    hipMemsetAsync(pooled, 0, (size_t)N_GRAPHS * 128 * sizeof(unsigned), stream);
    k_pool_max<<<(N * 128 + 255) / 256, 256, 0, stream>>>(bufB, b3, batch, pooled, N);

    // head
    k_final<<<N_GRAPHS, 64, 0, stream>>>((const float*)pooled, Wl, bl, out);
}

// Round 2
// 889.808 us; speedup vs baseline: 4.8813x; 4.8813x over previous
//
#include <hip/hip_runtime.h>
#include <hip/hip_bf16.h>

#define N_NODES 100000
#define N_EDGES 1600000
#define HID 128
#define N_GRAPHS 512
#define SCAN_B 256

// ---------------- CSR build: histogram / scan / scatter ----------------

__global__ void k_hist(const int* __restrict__ dst, int e, int* __restrict__ cnt) {
    int i = blockIdx.x * 256 + threadIdx.x;
    if (i < e) atomicAdd(&cnt[dst[i]], 1);
}

__global__ void k_deg_fin(const int* __restrict__ cnt, float* __restrict__ dis,
                          float* __restrict__ dinv, int n) {
    int i = blockIdx.x * 256 + threadIdx.x;
    if (i < n) {
        float d = (float)(cnt[i] + 1);   // +1 self-loop
        dis[i] = rsqrtf(d);
        dinv[i] = 1.0f / d;
    }
}

__global__ void k_scan1(const int* __restrict__ cnt, int* __restrict__ pre,
                        int* __restrict__ bsum, int n) {
    __shared__ int s[SCAN_B];
    int t = threadIdx.x;
    int i = blockIdx.x * SCAN_B + t;
    int v = (i < n) ? cnt[i] : 0;
    s[t] = v;
    __syncthreads();
    for (int off = 1; off < SCAN_B; off <<= 1) {
        int u = (t >= off) ? s[t - off] : 0;
        __syncthreads();
        s[t] += u;
        __syncthreads();
    }
    if (i < n) pre[i] = s[t] - v;                     // exclusive
    if (t == SCAN_B - 1) bsum[blockIdx.x] = s[t];     // block total
}

__global__ void k_scan2(int* __restrict__ bsum, int nb) {
    __shared__ int s[512];
    int t = threadIdx.x;
    int v = (t < nb) ? bsum[t] : 0;
    s[t] = v;
    __syncthreads();
    for (int off = 1; off < 512; off <<= 1) {
        int u = (t >= off) ? s[t - off] : 0;
        __syncthreads();
        s[t] += u;
        __syncthreads();
    }
    if (t < nb) bsum[t] = s[t] - v;                   // exclusive
}

__global__ void k_scan3(int* __restrict__ pre, const int* __restrict__ bsum,
                        int* __restrict__ cursor, int n, int e) {
    int i = blockIdx.x * SCAN_B + threadIdx.x;
    if (i < n) {
        int r = pre[i] + bsum[blockIdx.x];
        pre[i] = r;
        cursor[i] = r;
    }
    if (i == 0) pre[n] = e;
}

__global__ void k_scatter(const int* __restrict__ ei, const float* __restrict__ dis,
                          int* __restrict__ cursor, int* __restrict__ csrc,
                          float* __restrict__ cw, int e) {
    int i = blockIdx.x * 256 + threadIdx.x;
    if (i >= e) return;
    int s = ei[i];
    int d = ei[N_EDGES + i];
    int pos = atomicAdd(&cursor[d], 1);
    csrc[pos] = s;
    cw[pos] = dis[s] * dis[d];
}

// ---------------- layer 1: x (N x 7) @ W1 (7 x 128) ----------------

__global__ void k_linear1(const float* __restrict__ x, const float* __restrict__ W1,
                          float* __restrict__ hw, int n) {
    __shared__ float W1s[7 * 128];
    int tid = threadIdx.x;
    for (int i = tid; i < 7 * 128; i += 256) W1s[i] = W1[i];
    __syncthreads();
    int node = blockIdx.x * 2 + (tid >> 7);
    if (node >= n) return;
    int c = tid & 127;
    const float* xr = x + (size_t)node * 7;
    float acc = 0.f;
#pragma unroll
    for (int k = 0; k < 7; ++k) acc += xr[k] * W1s[k * 128 + c];
    hw[(size_t)node * 128 + c] = acc;
}

// ---------------- gather aggregation: agg[d] = hw[d]*dinv[d] + sum hw[s]*w ----------------
// one wave per node; 64 lanes x float2 = 128 channels

__launch_bounds__(256) __global__
void k_gather(const int* __restrict__ rowptr, const int* __restrict__ csrc,
              const float* __restrict__ cw, const float* __restrict__ dinv,
              const float* __restrict__ hw, float* __restrict__ agg, int n) {
    int node = blockIdx.x * 4 + (threadIdx.x >> 6);
    if (node >= n) return;
    int lane = threadIdx.x & 63;
    const float2* hw2 = (const float2*)hw;
    int beg = rowptr[node];
    int end = rowptr[node + 1];
    float di = dinv[node];
    float2 acc = hw2[(size_t)node * 64 + lane];
    acc.x *= di;
    acc.y *= di;
    int j = beg;
    for (; j + 1 < end; j += 2) {
        int s0 = csrc[j];
        int s1 = csrc[j + 1];
        float w0 = cw[j];
        float w1 = cw[j + 1];
        float2 v0 = hw2[(size_t)s0 * 64 + lane];
        float2 v1 = hw2[(size_t)s1 * 64 + lane];
        acc.x += v0.x * w0 + v1.x * w1;
        acc.y += v0.y * w0 + v1.y * w1;
    }
    if (j < end) {
        int s0 = csrc[j];
        float w0 = cw[j];
        float2 v0 = hw2[(size_t)s0 * 64 + lane];
        acc.x += v0.x * w0;
        acc.y += v0.y * w0;
    }
    ((float2*)agg)[(size_t)node * 64 + lane] = acc;
}

// ---------------- fused relu(agg+b) @ W (128x128) ----------------

#define GN 8
__launch_bounds__(256) __global__
void k_gemm128_fused(const float* __restrict__ aggin, const float* __restrict__ b,
                     const float* __restrict__ W, float* __restrict__ hwout, int n) {
    __shared__ float Ws[128 * 128];
    __shared__ float hs[GN * 128];
    int tid = threadIdx.x;
    const float4* W4 = (const float4*)W;
    float4* Ws4 = (float4*)Ws;
    for (int i = tid; i < 128 * 32; i += 256) Ws4[i] = W4[i];
    float4 bb = ((const float4*)b)[tid & 31];
    __syncthreads();

    int nsub = tid >> 5;   // 0..7 node slot
    int cg = tid & 31;     // float4 channel group
    for (int base = blockIdx.x * GN; base < n; base += gridDim.x * GN) {
        int nload = base + nsub;
        float4 v = make_float4(0.f, 0.f, 0.f, 0.f);
        if (nload < n) {
            v = ((const float4*)aggin)[(size_t)nload * 32 + cg];
            v.x = fmaxf(v.x + bb.x, 0.f);
            v.y = fmaxf(v.y + bb.y, 0.f);
            v.z = fmaxf(v.z + bb.z, 0.f);
            v.w = fmaxf(v.w + bb.w, 0.f);
        }
        __syncthreads();   // previous iteration's reads done
        ((float4*)hs)[tid] = v;
        __syncthreads();
        int node = base + nsub;
        if (node < n) {
            float4 acc = make_float4(0.f, 0.f, 0.f, 0.f);
            const float* hrow = &hs[nsub * 128];
#pragma unroll 8
            for (int k = 0; k < 128; ++k) {
                float hv = hrow[k];
                float4 wv = Ws4[k * 32 + cg];
                acc.x += hv * wv.x; acc.y += hv * wv.y;
                acc.z += hv * wv.z; acc.w += hv * wv.w;
            }
            ((float4*)hwout)[(size_t)node * 32 + cg] = acc;
        }
    }
}

// ---------------- pooling: segment_max(relu(agg+b)) via atomicMax on float bits ----------------

__global__ void k_pool_max(const float* __restrict__ agg, const float* __restrict__ b,
                           const int* __restrict__ batch, unsigned* __restrict__ pooled, int n) {
    int idx = blockIdx.x * 256 + threadIdx.x;
    int node = idx >> 7;
    if (node >= n) return;
    int c = idx & 127;
    int g = batch[node];
    float v = agg[(size_t)node * 128 + c] + b[c];
    v = fmaxf(v, 0.f);
    atomicMax(&pooled[(size_t)g * 128 + c], __float_as_uint(v));
}

// ---------------- head: out[g] = pooled[g] @ Wl + bl ----------------

__global__ void k_final(const float* __restrict__ pooled, const float* __restrict__ Wl,
                        const float* __restrict__ bl, float* __restrict__ out) {
    int g = blockIdx.x;
    int t = threadIdx.x;  // 64 threads
    float p0 = pooled[(size_t)g * 128 + t];
    float p1 = pooled[(size_t)g * 128 + t + 64];
    float a0 = p0 * Wl[t * 2 + 0] + p1 * Wl[(t + 64) * 2 + 0];
    float a1 = p0 * Wl[t * 2 + 1] + p1 * Wl[(t + 64) * 2 + 1];
#pragma unroll
    for (int off = 32; off > 0; off >>= 1) {
        a0 += __shfl_down(a0, off);
        a1 += __shfl_down(a1, off);
    }
    if (t == 0) {
        out[g * 2 + 0] = a0 + bl[0];
        out[g * 2 + 1] = a1 + bl[1];
    }
}

// ---------------- launch ----------------

extern "C" void kernel_launch(void* const* d_in, const int* in_sizes, int n_in,
                              void* d_out, int out_size, void* d_ws, size_t ws_size,
                              hipStream_t stream) {
    const float* x  = (const float*)d_in[0];
    const int*   ei = (const int*)d_in[1];
    const int*   batch = (const int*)d_in[2];
    const float* W1 = (const float*)d_in[3];
    const float* b1 = (const float*)d_in[4];
    const float* W2 = (const float*)d_in[5];
    const float* b2 = (const float*)d_in[6];
    const float* W3 = (const float*)d_in[7];
    const float* b3 = (const float*)d_in[8];
    const float* Wl = (const float*)d_in[9];
    const float* bl = (const float*)d_in[10];
    float* out = (float*)d_out;

    const int N = N_NODES, E = N_EDGES;

    // workspace layout
    char* ws = (char*)d_ws;
    float* bufA = (float*)ws;                               // N*128 (hw)
    float* bufB = bufA + (size_t)N * 128;                   // N*128 (agg)
    unsigned* pooled = (unsigned*)(bufB + (size_t)N * 128); // G*128
    float* dis  = (float*)(pooled + (size_t)N_GRAPHS * 128);
    float* dinv = dis + N;
    int*   cnt  = (int*)(dinv + N);                         // N
    int*   rowptr = cnt + N;                                // N+1
    int*   cursor = rowptr + N + 2;                         // N
    int*   bsum   = cursor + N;                             // 512
    int*   csrc   = bsum + 512;                             // E
    float* cw     = (float*)(csrc + E);                     // E

    int nb256 = (N + 255) / 256;   // 391
    int eb256 = (E + 255) / 256;   // 6250

    // CSR build + norms
    hipMemsetAsync(cnt, 0, (size_t)N * sizeof(int), stream);
    k_hist<<<eb256, 256, 0, stream>>>(ei + E, E, cnt);
    k_deg_fin<<<nb256, 256, 0, stream>>>(cnt, dis, dinv, N);
    k_scan1<<<nb256, SCAN_B, 0, stream>>>(cnt, rowptr, bsum, N);
    k_scan2<<<1, 512, 0, stream>>>(bsum, nb256);
    k_scan3<<<nb256, SCAN_B, 0, stream>>>(rowptr, bsum, cursor, N, E);
    k_scatter<<<eb256, 256, 0, stream>>>(ei, dis, cursor, csrc, cw, E);

    int ggrid = (N + 3) / 4;       // 4 waves (nodes) per block
    int gemm_grid = 512;

    // layer 1
    k_linear1<<<(N + 1) / 2, 256, 0, stream>>>(x, W1, bufA, N);
    k_gather<<<ggrid, 256, 0, stream>>>(rowptr, csrc, cw, dinv, bufA, bufB, N);

    // layer 2
    k_gemm128_fused<<<gemm_grid, 256, 0, stream>>>(bufB, b1, W2, bufA, N);
    k_gather<<<ggrid, 256, 0, stream>>>(rowptr, csrc, cw, dinv, bufA, bufB, N);

    // layer 3
    k_gemm128_fused<<<gemm_grid, 256, 0, stream>>>(bufB, b2, W3, bufA, N);
    k_gather<<<ggrid, 256, 0, stream>>>(rowptr, csrc, cw, dinv, bufA, bufB, N);

    // pooling
    hipMemsetAsync(pooled, 0, (size_t)N_GRAPHS * 128 * sizeof(unsigned), stream);
    k_pool_max<<<(N * 128 + 255) / 256, 256, 0, stream>>>(bufB, b3, batch, pooled, N);

    // head
    k_final<<<N_GRAPHS, 64, 0, stream>>>((const float*)pooled, Wl, bl, out);
}